// Round 1
// baseline (393.146 us; speedup 1.0000x reference)
//
#include <hip/hip_runtime.h>
#include <math.h>

#define NN 50000
#define NE 500000
#define IC 128
#define OC 256

// ---------------- degree / normalization ----------------

__global__ void k_deg_init(float* __restrict__ deg) {
    int i = blockIdx.x * 256 + threadIdx.x;
    if (i < NN) deg[i] = 1.0f;   // self-loop weight 1
}

__global__ void k_deg_edges(const int* __restrict__ col,
                            const float* __restrict__ ew,
                            float* __restrict__ deg) {
    int e = blockIdx.x * 256 + threadIdx.x;
    if (e < NE) {
        float w = 1.0f / (1.0f + expf(-ew[e]));   // sigmoid
        atomicAdd(&deg[col[e]], w);
    }
}

__global__ void k_dinv(float* __restrict__ deg) {
    int i = blockIdx.x * 256 + threadIdx.x;
    if (i < NN) {
        float d = deg[i];
        deg[i] = (d > 0.0f) ? rsqrtf(d) : 0.0f;
    }
}

// ---------------- aggregation of raw features (128ch) ----------------
// agg[i] = x[i] * dinv[i]^2   (self-loop term; also zero-inits agg)

__global__ void k_agg_init(const float* __restrict__ x,
                           const float* __restrict__ dinv,
                           float* __restrict__ agg) {
    int idx = blockIdx.x * 256 + threadIdx.x;   // float4 index
    const int NV = NN * (IC / 4);
    if (idx >= NV) return;
    int n = idx / (IC / 4);
    float di = dinv[n];
    float s = di * di;
    float4 v = ((const float4*)x)[idx];
    v.x *= s; v.y *= s; v.z *= s; v.w *= s;
    ((float4*)agg)[idx] = v;
}

// agg[col] += x[row] * (dinv[row]*sigmoid(ew)*dinv[col]); 128 threads per edge
__global__ void k_scatter(const float* __restrict__ x,
                          const int* __restrict__ row,
                          const int* __restrict__ col,
                          const float* __restrict__ ew,
                          const float* __restrict__ dinv,
                          float* __restrict__ agg) {
    int e = blockIdx.x * 2 + (threadIdx.x >> 7);
    if (e >= NE) return;
    int c = threadIdx.x & 127;
    int r = row[e], t = col[e];
    float w = 1.0f / (1.0f + expf(-ew[e]));
    float nrm = dinv[r] * w * dinv[t];
    atomicAdd(&agg[(size_t)t * IC + c], x[(size_t)r * IC + c] * nrm);
}

// ---------------- GEMM: out = agg @ W + b ----------------
// M=50000 K=128 N=256, f32. 64x64 tile, 256 threads, 4x4 microtile, full-K LDS.

__global__ __launch_bounds__(256) void k_gemm(const float* __restrict__ agg,
                                              const float* __restrict__ Wm,
                                              const float* __restrict__ bias,
                                              float* __restrict__ out) {
    __shared__ float As[64][IC + 4];   // stride 132: bank=(4*row+k)%32, max 2-way (free)
    __shared__ float Bs[IC][64];       // row-aligned for float4 reads
    const int tid = threadIdx.x;
    const int tx = tid & 15;           // col group 0..15
    const int ty = tid >> 4;           // row group 0..15
    const int m0 = blockIdx.y * 64;
    const int n0 = blockIdx.x * 64;

    // stage As: 64 rows x 128 floats = 2048 float4, 8 per thread
    #pragma unroll
    for (int i = 0; i < 8; ++i) {
        int fi = tid + i * 256;            // float4 id
        int rr = fi >> 5;                  // 32 float4 per row
        int cc = (fi & 31) << 2;
        int gr = m0 + rr;
        float4 v = (gr < NN) ? ((const float4*)(agg + (size_t)gr * IC))[fi & 31]
                             : make_float4(0.f, 0.f, 0.f, 0.f);
        *(float4*)&As[rr][cc] = v;
    }
    // stage Bs: 128 rows x 64 floats = 2048 float4 (16 per k-row)
    #pragma unroll
    for (int i = 0; i < 8; ++i) {
        int fi = tid + i * 256;
        int kk = fi >> 4;
        int cc = (fi & 15) << 2;
        float4 v = ((const float4*)(Wm + (size_t)kk * OC + n0))[fi & 15];
        *(float4*)&Bs[kk][cc] = v;
    }
    __syncthreads();

    float acc[4][4] = {};
    #pragma unroll 4
    for (int k = 0; k < IC; ++k) {
        float a0 = As[ty * 4 + 0][k];
        float a1 = As[ty * 4 + 1][k];
        float a2 = As[ty * 4 + 2][k];
        float a3 = As[ty * 4 + 3][k];
        float4 wv = *(const float4*)&Bs[k][tx * 4];
        acc[0][0] += a0 * wv.x; acc[0][1] += a0 * wv.y; acc[0][2] += a0 * wv.z; acc[0][3] += a0 * wv.w;
        acc[1][0] += a1 * wv.x; acc[1][1] += a1 * wv.y; acc[1][2] += a1 * wv.z; acc[1][3] += a1 * wv.w;
        acc[2][0] += a2 * wv.x; acc[2][1] += a2 * wv.y; acc[2][2] += a2 * wv.z; acc[2][3] += a2 * wv.w;
        acc[3][0] += a3 * wv.x; acc[3][1] += a3 * wv.y; acc[3][2] += a3 * wv.z; acc[3][3] += a3 * wv.w;
    }

    float4 bv = *(const float4*)&bias[n0 + tx * 4];
    #pragma unroll
    for (int i = 0; i < 4; ++i) {
        int gr = m0 + ty * 4 + i;
        if (gr < NN) {
            float4 o;
            o.x = acc[i][0] + bv.x;
            o.y = acc[i][1] + bv.y;
            o.z = acc[i][2] + bv.z;
            o.w = acc[i][3] + bv.w;
            *(float4*)(out + (size_t)gr * OC + n0 + tx * 4) = o;
        }
    }
}

// ---------------- launch ----------------

extern "C" void kernel_launch(void* const* d_in, const int* in_sizes, int n_in,
                              void* d_out, int out_size, void* d_ws, size_t ws_size,
                              hipStream_t stream) {
    const float* x  = (const float*)d_in[0];
    const float* W  = (const float*)d_in[1];
    const float* b  = (const float*)d_in[2];
    const int*   ei = (const int*)d_in[3];    // [2, NE] flattened; int64 -> int32 by harness
    const float* ew = (const float*)d_in[4];
    const int* row = ei;                       // source
    const int* col = ei + NE;                  // target
    float* out = (float*)d_out;

    float* deg = (float*)d_ws;                 // 50000 f32 (becomes dinv in place)
    float* agg = (float*)d_ws + 50176;         // 50000 x 128 f32 = 25.6 MB

    k_deg_init<<<(NN + 255) / 256, 256, 0, stream>>>(deg);
    k_deg_edges<<<(NE + 255) / 256, 256, 0, stream>>>(col, ew, deg);
    k_dinv<<<(NN + 255) / 256, 256, 0, stream>>>(deg);
    k_agg_init<<<(NN * (IC / 4) + 255) / 256, 256, 0, stream>>>(x, deg, agg);
    k_scatter<<<NE / 2, 256, 0, stream>>>(x, row, col, ew, deg, agg);
    k_gemm<<<dim3(OC / 64, (NN + 63) / 64), 256, 0, stream>>>(agg, W, b, out);
}

// Round 2
// 273.867 us; speedup vs baseline: 1.4355x; 1.4355x over previous
//
#include <hip/hip_runtime.h>
#include <math.h>

#define NN 50000
#define NE 500000
#define IC 128
#define OC 256
#define NPAD 50176            // 196 * 256
#define NB 196                // scan blocks

// ---------------- init: deg=1 (self-loop), count=0 ----------------
__global__ void k_init(float* __restrict__ deg, int* __restrict__ count) {
    int i = blockIdx.x * 256 + threadIdx.x;   // i < NPAD
    deg[i] = 1.0f;
    count[i] = 0;
}

// ---------------- edge pass 1: degree + histogram ----------------
__global__ void k_edge_pass1(const int* __restrict__ col,
                             const float* __restrict__ ew,
                             float* __restrict__ deg,
                             int* __restrict__ count) {
    int e = blockIdx.x * 256 + threadIdx.x;
    if (e < NE) {
        int c = col[e];
        float w = 1.0f / (1.0f + expf(-ew[e]));   // sigmoid
        atomicAdd(&deg[c], w);
        atomicAdd(&count[c], 1);
    }
}

__global__ void k_dinv(float* __restrict__ deg) {
    int i = blockIdx.x * 256 + threadIdx.x;   // i < NPAD
    float d = deg[i];
    deg[i] = (d > 0.0f) ? rsqrtf(d) : 0.0f;
}

// ---------------- exclusive scan of count[NPAD] -> start ----------------
__global__ void k_scan1(const int* __restrict__ count,
                        int* __restrict__ pre,
                        int* __restrict__ bsum) {
    __shared__ int s[256];
    int t = threadIdx.x;
    int i = blockIdx.x * 256 + t;
    int v = count[i];
    s[t] = v;
    __syncthreads();
    #pragma unroll
    for (int off = 1; off < 256; off <<= 1) {
        int add = (t >= off) ? s[t - off] : 0;
        __syncthreads();
        s[t] += add;
        __syncthreads();
    }
    pre[i] = s[t] - v;                 // exclusive within block
    if (t == 255) bsum[blockIdx.x] = s[255];
}

__global__ void k_scan2(int* __restrict__ bsum) {
    __shared__ int s[256];
    int t = threadIdx.x;
    int v = (t < NB) ? bsum[t] : 0;
    s[t] = v;
    __syncthreads();
    #pragma unroll
    for (int off = 1; off < 256; off <<= 1) {
        int add = (t >= off) ? s[t - off] : 0;
        __syncthreads();
        s[t] += add;
        __syncthreads();
    }
    if (t < NB) bsum[t] = s[t] - v;    // exclusive block offsets
}

// start[i] = pre[i] + bsum[bid]; also zero count for reuse as fill cursor
__global__ void k_scan3(const int* __restrict__ pre,
                        const int* __restrict__ bsum,
                        int* __restrict__ start,
                        int* __restrict__ count) {
    int i = blockIdx.x * 256 + threadIdx.x;
    start[i] = pre[i] + bsum[blockIdx.x];
    count[i] = 0;
}

// ---------------- edge pass 2: fill CSR buckets with (row, norm) ----------------
__global__ void k_fill(const int* __restrict__ row,
                       const int* __restrict__ col,
                       const float* __restrict__ ew,
                       const float* __restrict__ dinv,
                       const int* __restrict__ start,
                       int* __restrict__ cursor,
                       int* __restrict__ erow,
                       float* __restrict__ enrm) {
    int e = blockIdx.x * 256 + threadIdx.x;
    if (e < NE) {
        int r = row[e], t = col[e];
        float w = 1.0f / (1.0f + expf(-ew[e]));
        float nrm = dinv[r] * w * dinv[t];
        int pos = start[t] + atomicAdd(&cursor[t], 1);
        erow[pos] = r;
        enrm[pos] = nrm;
    }
}

// ---------------- gather: agg[n] = x[n]*dinv^2 + sum_e x[erow]*enrm ----------------
// 8 nodes per block, 32 lanes per node, float4 per lane (128 ch)
__global__ __launch_bounds__(256) void k_gather(const float* __restrict__ x,
                                                const int* __restrict__ start,
                                                const int* __restrict__ erow,
                                                const float* __restrict__ enrm,
                                                const float* __restrict__ dinv,
                                                float* __restrict__ agg) {
    int n = blockIdx.x * 8 + (threadIdx.x >> 5);
    if (n >= NN) return;
    int lane = threadIdx.x & 31;
    const float4* x4 = (const float4*)x;
    float di = dinv[n];
    float s2 = di * di;
    float4 acc = x4[(size_t)n * 32 + lane];
    acc.x *= s2; acc.y *= s2; acc.z *= s2; acc.w *= s2;
    int s = start[n], t = start[n + 1];
    for (int e = s; e < t; ++e) {
        int r = erow[e];
        float w = enrm[e];
        float4 xv = x4[(size_t)r * 32 + lane];
        acc.x += xv.x * w; acc.y += xv.y * w; acc.z += xv.z * w; acc.w += xv.w * w;
    }
    ((float4*)agg)[(size_t)n * 32 + lane] = acc;
}

// ---------------- GEMM: out = agg @ W + b ----------------
__global__ __launch_bounds__(256) void k_gemm(const float* __restrict__ agg,
                                              const float* __restrict__ Wm,
                                              const float* __restrict__ bias,
                                              float* __restrict__ out) {
    __shared__ float As[64][IC + 4];
    __shared__ float Bs[IC][64];
    const int tid = threadIdx.x;
    const int tx = tid & 15;
    const int ty = tid >> 4;
    const int m0 = blockIdx.y * 64;
    const int n0 = blockIdx.x * 64;

    #pragma unroll
    for (int i = 0; i < 8; ++i) {
        int fi = tid + i * 256;
        int rr = fi >> 5;
        int cc = (fi & 31) << 2;
        int gr = m0 + rr;
        float4 v = (gr < NN) ? ((const float4*)(agg + (size_t)gr * IC))[fi & 31]
                             : make_float4(0.f, 0.f, 0.f, 0.f);
        *(float4*)&As[rr][cc] = v;
    }
    #pragma unroll
    for (int i = 0; i < 8; ++i) {
        int fi = tid + i * 256;
        int kk = fi >> 4;
        int cc = (fi & 15) << 2;
        float4 v = ((const float4*)(Wm + (size_t)kk * OC + n0))[fi & 15];
        *(float4*)&Bs[kk][cc] = v;
    }
    __syncthreads();

    float acc[4][4] = {};
    #pragma unroll 4
    for (int k = 0; k < IC; ++k) {
        float a0 = As[ty * 4 + 0][k];
        float a1 = As[ty * 4 + 1][k];
        float a2 = As[ty * 4 + 2][k];
        float a3 = As[ty * 4 + 3][k];
        float4 wv = *(const float4*)&Bs[k][tx * 4];
        acc[0][0] += a0 * wv.x; acc[0][1] += a0 * wv.y; acc[0][2] += a0 * wv.z; acc[0][3] += a0 * wv.w;
        acc[1][0] += a1 * wv.x; acc[1][1] += a1 * wv.y; acc[1][2] += a1 * wv.z; acc[1][3] += a1 * wv.w;
        acc[2][0] += a2 * wv.x; acc[2][1] += a2 * wv.y; acc[2][2] += a2 * wv.z; acc[2][3] += a2 * wv.w;
        acc[3][0] += a3 * wv.x; acc[3][1] += a3 * wv.y; acc[3][2] += a3 * wv.z; acc[3][3] += a3 * wv.w;
    }

    float4 bv = *(const float4*)&bias[n0 + tx * 4];
    #pragma unroll
    for (int i = 0; i < 4; ++i) {
        int gr = m0 + ty * 4 + i;
        if (gr < NN) {
            float4 o;
            o.x = acc[i][0] + bv.x;
            o.y = acc[i][1] + bv.y;
            o.z = acc[i][2] + bv.z;
            o.w = acc[i][3] + bv.w;
            *(float4*)(out + (size_t)gr * OC + n0 + tx * 4) = o;
        }
    }
}

// ---------------- launch ----------------
extern "C" void kernel_launch(void* const* d_in, const int* in_sizes, int n_in,
                              void* d_out, int out_size, void* d_ws, size_t ws_size,
                              hipStream_t stream) {
    const float* x  = (const float*)d_in[0];
    const float* W  = (const float*)d_in[1];
    const float* b  = (const float*)d_in[2];
    const int*   ei = (const int*)d_in[3];
    const float* ew = (const float*)d_in[4];
    const int* row = ei;            // source
    const int* col = ei + NE;       // target
    float* out = (float*)d_out;

    // workspace layout (4-byte words)
    char* w0 = (char*)d_ws;
    float* deg   = (float*)w0;                       w0 += NPAD * 4;     // -> dinv
    int*   count = (int*)w0;                         w0 += NPAD * 4;     // also fill cursor
    int*   pre   = (int*)w0;                         w0 += NPAD * 4;
    int*   bsum  = (int*)w0;                         w0 += 256 * 4;
    int*   start = (int*)w0;                         w0 += NPAD * 4;     // start[NN] = NE lives inside
    int*   erow  = (int*)w0;                         w0 += NE * 4;
    float* enrm  = (float*)w0;                       w0 += NE * 4;
    float* agg   = (float*)w0;                       // NN*IC f32 = 25.6 MB

    k_init      <<<NB, 256, 0, stream>>>(deg, count);
    k_edge_pass1<<<(NE + 255) / 256, 256, 0, stream>>>(col, ew, deg, count);
    k_dinv      <<<NB, 256, 0, stream>>>(deg);
    k_scan1     <<<NB, 256, 0, stream>>>(count, pre, bsum);
    k_scan2     <<<1, 256, 0, stream>>>(bsum);
    k_scan3     <<<NB, 256, 0, stream>>>(pre, bsum, start, count);
    k_fill      <<<(NE + 255) / 256, 256, 0, stream>>>(row, col, ew, deg, start, count, erow, enrm);
    k_gather    <<<(NN + 7) / 8, 256, 0, stream>>>(x, start, erow, enrm, deg, agg);
    k_gemm      <<<dim3(OC / 64, (NN + 63) / 64), 256, 0, stream>>>(agg, W, b, out);
}

// Round 3
// 243.125 us; speedup vs baseline: 1.6171x; 1.1264x over previous
//
#include <hip/hip_runtime.h>
#include <hip/hip_bf16.h>
#include <math.h>

#define NN 50000
#define NE 500000
#define IC 128
#define OC 256
#define NPAD 50176            // 196 * 256
#define NB 196                // scan blocks

typedef short bf16x8 __attribute__((ext_vector_type(8)));
typedef float f32x4 __attribute__((ext_vector_type(4)));

static __device__ inline unsigned short f2b(float f) {
    __hip_bfloat16 h = __float2bfloat16(f);   // RNE
    return *reinterpret_cast<unsigned short*>(&h);
}

// ---------------- init: deg=1 (self-loop), count=0 ----------------
__global__ void k_init(float* __restrict__ deg, int* __restrict__ count) {
    int i = blockIdx.x * 256 + threadIdx.x;   // i < NPAD
    deg[i] = 1.0f;
    count[i] = 0;
}

// ---------------- edge pass 1: degree + histogram ----------------
__global__ void k_edge_pass1(const int* __restrict__ col,
                             const float* __restrict__ ew,
                             float* __restrict__ deg,
                             int* __restrict__ count) {
    int e = blockIdx.x * 256 + threadIdx.x;
    if (e < NE) {
        int c = col[e];
        float w = 1.0f / (1.0f + expf(-ew[e]));   // sigmoid
        atomicAdd(&deg[c], w);
        atomicAdd(&count[c], 1);
    }
}

__global__ void k_dinv(float* __restrict__ deg) {
    int i = blockIdx.x * 256 + threadIdx.x;   // i < NPAD
    float d = deg[i];
    deg[i] = (d > 0.0f) ? rsqrtf(d) : 0.0f;
}

// ---------------- exclusive scan of count[NPAD] -> start ----------------
__global__ void k_scan1(const int* __restrict__ count,
                        int* __restrict__ pre,
                        int* __restrict__ bsum) {
    __shared__ int s[256];
    int t = threadIdx.x;
    int i = blockIdx.x * 256 + t;
    int v = count[i];
    s[t] = v;
    __syncthreads();
    #pragma unroll
    for (int off = 1; off < 256; off <<= 1) {
        int add = (t >= off) ? s[t - off] : 0;
        __syncthreads();
        s[t] += add;
        __syncthreads();
    }
    pre[i] = s[t] - v;
    if (t == 255) bsum[blockIdx.x] = s[255];
}

__global__ void k_scan2(int* __restrict__ bsum) {
    __shared__ int s[256];
    int t = threadIdx.x;
    int v = (t < NB) ? bsum[t] : 0;
    s[t] = v;
    __syncthreads();
    #pragma unroll
    for (int off = 1; off < 256; off <<= 1) {
        int add = (t >= off) ? s[t - off] : 0;
        __syncthreads();
        s[t] += add;
        __syncthreads();
    }
    if (t < NB) bsum[t] = s[t] - v;
}

__global__ void k_scan3(const int* __restrict__ pre,
                        const int* __restrict__ bsum,
                        int* __restrict__ start,
                        int* __restrict__ count) {
    int i = blockIdx.x * 256 + threadIdx.x;
    start[i] = pre[i] + bsum[blockIdx.x];
    count[i] = 0;
}

// ---------------- edge pass 2: fill CSR buckets with (row, norm) ----------------
__global__ void k_fill(const int* __restrict__ row,
                       const int* __restrict__ col,
                       const float* __restrict__ ew,
                       const float* __restrict__ dinv,
                       const int* __restrict__ start,
                       int* __restrict__ cursor,
                       int* __restrict__ erow,
                       float* __restrict__ enrm) {
    int e = blockIdx.x * 256 + threadIdx.x;
    if (e < NE) {
        int r = row[e], t = col[e];
        float w = 1.0f / (1.0f + expf(-ew[e]));
        float nrm = dinv[r] * w * dinv[t];
        int pos = start[t] + atomicAdd(&cursor[t], 1);
        erow[pos] = r;
        enrm[pos] = nrm;
    }
}

// ---------------- W -> W^T bf16  (WT[n][k]) ----------------
__global__ void k_wt(const float* __restrict__ W, unsigned short* __restrict__ WT) {
    int t = blockIdx.x * 256 + threadIdx.x;   // t < IC*OC
    int k = t >> 8;        // /OC
    int n = t & 255;
    WT[n * IC + k] = f2b(W[t]);
}

// ---------------- gather: agg_bf16[n] = bf16( x[n]*dinv^2 + sum_e x[erow]*enrm ) ----------------
__global__ __launch_bounds__(256) void k_gather(const float* __restrict__ x,
                                                const int* __restrict__ start,
                                                const int* __restrict__ erow,
                                                const float* __restrict__ enrm,
                                                const float* __restrict__ dinv,
                                                unsigned short* __restrict__ aggb) {
    int n = blockIdx.x * 8 + (threadIdx.x >> 5);
    if (n >= NN) return;
    int lane = threadIdx.x & 31;
    const float4* x4 = (const float4*)x;
    float di = dinv[n];
    float s2 = di * di;
    float4 acc = x4[(size_t)n * 32 + lane];
    acc.x *= s2; acc.y *= s2; acc.z *= s2; acc.w *= s2;
    int s = start[n], t = start[n + 1];
    for (int e = s; e < t; ++e) {
        int r = erow[e];
        float w = enrm[e];
        float4 xv = x4[(size_t)r * 32 + lane];
        acc.x += xv.x * w; acc.y += xv.y * w; acc.z += xv.z * w; acc.w += xv.w * w;
    }
    ushort4 o;
    o.x = f2b(acc.x); o.y = f2b(acc.y); o.z = f2b(acc.z); o.w = f2b(acc.w);
    ((ushort4*)aggb)[(size_t)n * 32 + lane] = o;   // 8 B/lane, coalesced
}

// ---------------- GEMM: out = agg_bf16 @ WT^T + b  (MFMA, no LDS) ----------------
// grid (2, 391); block 256 = 4 waves in 2x2; wave tile 64x64; 4x4 microtiles of 16x16x32
__global__ __launch_bounds__(256) void k_gemm(const unsigned short* __restrict__ agg,
                                              const unsigned short* __restrict__ WT,
                                              const float* __restrict__ bias,
                                              float* __restrict__ out) {
    const int w = threadIdx.x >> 6;
    const int lane = threadIdx.x & 63;
    const int m0 = blockIdx.y * 128 + (w >> 1) * 64;
    const int n0 = blockIdx.x * 128 + (w & 1) * 64;
    const int lm = lane & 15;
    const int lk = (lane >> 4) * 8;

    f32x4 acc[4][4] = {};
    #pragma unroll
    for (int ks = 0; ks < 4; ++ks) {
        const int k0 = ks * 32 + lk;
        bf16x8 af[4], bfr[4];
        #pragma unroll
        for (int i = 0; i < 4; ++i)
            af[i] = *(const bf16x8*)(agg + (size_t)(m0 + i * 16 + lm) * IC + k0);
        #pragma unroll
        for (int j = 0; j < 4; ++j)
            bfr[j] = *(const bf16x8*)(WT + (size_t)(n0 + j * 16 + lm) * IC + k0);
        #pragma unroll
        for (int i = 0; i < 4; ++i)
            #pragma unroll
            for (int j = 0; j < 4; ++j)
                acc[i][j] = __builtin_amdgcn_mfma_f32_16x16x32_bf16(af[i], bfr[j], acc[i][j], 0, 0, 0);
    }

    // C/D layout: col = lane&15, row = (lane>>4)*4 + reg   [m89-verified]
    const int col = lane & 15;
    const int rbase = (lane >> 4) * 4;
    #pragma unroll
    for (int j = 0; j < 4; ++j) {
        float bv = bias[n0 + j * 16 + col];
        #pragma unroll
        for (int i = 0; i < 4; ++i) {
            #pragma unroll
            for (int r = 0; r < 4; ++r) {
                int grow = m0 + i * 16 + rbase + r;
                if (grow < NN)
                    out[(size_t)grow * OC + n0 + j * 16 + col] = acc[i][j][r] + bv;
            }
        }
    }
}

// ---------------- launch ----------------
extern "C" void kernel_launch(void* const* d_in, const int* in_sizes, int n_in,
                              void* d_out, int out_size, void* d_ws, size_t ws_size,
                              hipStream_t stream) {
    const float* x  = (const float*)d_in[0];
    const float* W  = (const float*)d_in[1];
    const float* b  = (const float*)d_in[2];
    const int*   ei = (const int*)d_in[3];
    const float* ew = (const float*)d_in[4];
    const int* row = ei;            // source
    const int* col = ei + NE;       // target
    float* out = (float*)d_out;

    char* w0 = (char*)d_ws;
    float* deg   = (float*)w0;                w0 += NPAD * 4;    // -> dinv in place
    int*   count = (int*)w0;                  w0 += NPAD * 4;    // also fill cursor
    int*   pre   = (int*)w0;                  w0 += NPAD * 4;
    int*   bsum  = (int*)w0;                  w0 += 256 * 4;
    int*   start = (int*)w0;                  w0 += NPAD * 4;
    int*   erow  = (int*)w0;                  w0 += NE * 4;
    float* enrm  = (float*)w0;                w0 += NE * 4;
    unsigned short* WT   = (unsigned short*)w0;  w0 += IC * OC * 2;
    unsigned short* aggb = (unsigned short*)w0;  // NPAD*IC bf16 = 12.8 MB

    k_init      <<<NB, 256, 0, stream>>>(deg, count);
    k_edge_pass1<<<(NE + 255) / 256, 256, 0, stream>>>(col, ew, deg, count);
    k_dinv      <<<NB, 256, 0, stream>>>(deg);
    k_scan1     <<<NB, 256, 0, stream>>>(count, pre, bsum);
    k_scan2     <<<1, 256, 0, stream>>>(bsum);
    k_scan3     <<<NB, 256, 0, stream>>>(pre, bsum, start, count);
    k_fill      <<<(NE + 255) / 256, 256, 0, stream>>>(row, col, ew, deg, start, count, erow, enrm);
    k_wt        <<<(IC * OC) / 256, 256, 0, stream>>>(W, WT);
    k_gather    <<<(NN + 7) / 8, 256, 0, stream>>>(x, start, erow, enrm, deg, aggb);
    k_gemm      <<<dim3(2, (NN + 127) / 128), 256, 0, stream>>>(aggb, WT, b, out);
}

// Round 4
// 223.762 us; speedup vs baseline: 1.7570x; 1.0865x over previous
//
#include <hip/hip_runtime.h>
#include <hip/hip_bf16.h>
#include <math.h>

#define NN 50000
#define NE 500000
#define IC 128
#define OC 256
#define NPAD 50176            // 196 * 256
#define NB 196                // scan blocks

typedef short bf16x8 __attribute__((ext_vector_type(8)));
typedef float f32x4 __attribute__((ext_vector_type(4)));

static __device__ inline unsigned short f2b(float f) {
    __hip_bfloat16 h = __float2bfloat16(f);   // RNE
    return *reinterpret_cast<unsigned short*>(&h);
}
static __device__ inline float b2f(short u) {
    unsigned v = ((unsigned)(unsigned short)u) << 16;
    return __int_as_float(v);
}

// ---------------- init: deg=1 (self-loop), count=0 ----------------
__global__ void k_init(float* __restrict__ deg, int* __restrict__ count) {
    int i = blockIdx.x * 256 + threadIdx.x;   // i < NPAD
    deg[i] = 1.0f;
    count[i] = 0;
}

// ---------------- edge pass 1: degree + histogram ----------------
__global__ void k_edge_pass1(const int* __restrict__ col,
                             const float* __restrict__ ew,
                             float* __restrict__ deg,
                             int* __restrict__ count) {
    int e = blockIdx.x * 256 + threadIdx.x;
    if (e < NE) {
        int c = col[e];
        float w = 1.0f / (1.0f + expf(-ew[e]));   // sigmoid
        atomicAdd(&deg[c], w);
        atomicAdd(&count[c], 1);
    }
}

__global__ void k_dinv(float* __restrict__ deg) {
    int i = blockIdx.x * 256 + threadIdx.x;   // i < NPAD
    float d = deg[i];
    deg[i] = (d > 0.0f) ? rsqrtf(d) : 0.0f;
}

// ---------------- exclusive scan of count[NPAD] -> start (in place) ----------------
__global__ void k_scan1(const int* __restrict__ count,
                        int* __restrict__ start,
                        int* __restrict__ bsum) {
    __shared__ int s[256];
    int t = threadIdx.x;
    int i = blockIdx.x * 256 + t;
    int v = count[i];
    s[t] = v;
    __syncthreads();
    #pragma unroll
    for (int off = 1; off < 256; off <<= 1) {
        int add = (t >= off) ? s[t - off] : 0;
        __syncthreads();
        s[t] += add;
        __syncthreads();
    }
    start[i] = s[t] - v;               // exclusive within block
    if (t == 255) bsum[blockIdx.x] = s[255];
}

__global__ void k_scan2(int* __restrict__ bsum) {
    __shared__ int s[256];
    int t = threadIdx.x;
    int v = (t < NB) ? bsum[t] : 0;
    s[t] = v;
    __syncthreads();
    #pragma unroll
    for (int off = 1; off < 256; off <<= 1) {
        int add = (t >= off) ? s[t - off] : 0;
        __syncthreads();
        s[t] += add;
        __syncthreads();
    }
    if (t < NB) bsum[t] = s[t] - v;    // exclusive block offsets
}

__global__ void k_scan3(int* __restrict__ start,
                        const int* __restrict__ bsum,
                        int* __restrict__ count) {
    int i = blockIdx.x * 256 + threadIdx.x;
    start[i] += bsum[blockIdx.x];
    count[i] = 0;                       // reuse as fill cursor
}

// ---------------- edge pass 2: fill CSR buckets with packed (row, norm) ----------------
__global__ void k_fill(const int* __restrict__ row,
                       const int* __restrict__ col,
                       const float* __restrict__ ew,
                       const float* __restrict__ dinv,
                       const int* __restrict__ start,
                       int* __restrict__ cursor,
                       int2* __restrict__ epack) {
    int e = blockIdx.x * 256 + threadIdx.x;
    if (e < NE) {
        int r = row[e], t = col[e];
        float w = 1.0f / (1.0f + expf(-ew[e]));
        float nrm = dinv[r] * w * dinv[t];
        int pos = start[t] + atomicAdd(&cursor[t], 1);
        int2 p;
        p.x = r;
        p.y = __float_as_int(nrm);
        epack[pos] = p;                 // one 8B store per edge
    }
}

// ---------------- x -> bf16 ----------------
__global__ void k_xb(const float* __restrict__ x, unsigned short* __restrict__ xb) {
    int i = blockIdx.x * 256 + threadIdx.x;   // i < NN*IC/4
    if (i >= NN * (IC / 4)) return;
    float4 v = ((const float4*)x)[i];
    ushort4 o;
    o.x = f2b(v.x); o.y = f2b(v.y); o.z = f2b(v.z); o.w = f2b(v.w);
    ((ushort4*)xb)[i] = o;
}

// ---------------- W -> W^T bf16  (WT[n][k]) ----------------
__global__ void k_wt(const float* __restrict__ W, unsigned short* __restrict__ WT) {
    int t = blockIdx.x * 256 + threadIdx.x;   // t < IC*OC
    int k = t >> 8;        // /OC
    int n = t & 255;
    WT[n * IC + k] = f2b(W[t]);
}

// ---------------- gather (bf16): aggb[n] = bf16( xb[n]*dinv^2 + sum_e xb[r]*nrm ) ----------------
// 16 nodes per block, 16 lanes per node, bf16x8 (16B) per lane
__global__ __launch_bounds__(256) void k_gather(const unsigned short* __restrict__ xb,
                                                const int* __restrict__ start,
                                                const int2* __restrict__ epack,
                                                const float* __restrict__ dinv,
                                                unsigned short* __restrict__ aggb) {
    int n = blockIdx.x * 16 + (threadIdx.x >> 4);
    if (n >= NN) return;
    int lane = threadIdx.x & 15;
    const bf16x8* xv = (const bf16x8*)xb;     // row = 16 units of 8 bf16

    float di = dinv[n];
    float s2 = di * di;
    bf16x8 xs = xv[(size_t)n * 16 + lane];
    float acc[8];
    #pragma unroll
    for (int c = 0; c < 8; ++c) acc[c] = b2f(xs[c]) * s2;

    int s = start[n], t = start[n + 1];
    int e = s;
    for (; e + 2 <= t; e += 2) {              // 2x unroll for MLP
        int2 p0 = epack[e];
        int2 p1 = epack[e + 1];
        bf16x8 v0 = xv[(size_t)p0.x * 16 + lane];
        bf16x8 v1 = xv[(size_t)p1.x * 16 + lane];
        float w0 = __int_as_float(p0.y);
        float w1 = __int_as_float(p1.y);
        #pragma unroll
        for (int c = 0; c < 8; ++c) acc[c] += b2f(v0[c]) * w0;
        #pragma unroll
        for (int c = 0; c < 8; ++c) acc[c] += b2f(v1[c]) * w1;
    }
    if (e < t) {
        int2 p = epack[e];
        bf16x8 v = xv[(size_t)p.x * 16 + lane];
        float w = __int_as_float(p.y);
        #pragma unroll
        for (int c = 0; c < 8; ++c) acc[c] += b2f(v[c]) * w;
    }

    bf16x8 o;
    #pragma unroll
    for (int c = 0; c < 8; ++c) o[c] = (short)f2b(acc[c]);
    ((bf16x8*)aggb)[(size_t)n * 16 + lane] = o;
}

// ---------------- GEMM: out = aggb @ WT^T + b  (MFMA, no LDS, swapped operands) ----------------
// block 256 = 4 waves; block tile 64m x 128n; wave tile 32m x 64n; grid (2, 782)
__global__ __launch_bounds__(256) void k_gemm(const unsigned short* __restrict__ agg,
                                              const unsigned short* __restrict__ WT,
                                              const float* __restrict__ bias,
                                              float* __restrict__ out) {
    const int w = threadIdx.x >> 6;
    const int lane = threadIdx.x & 63;
    const int m0 = blockIdx.y * 64 + (w >> 1) * 32;
    const int n0 = blockIdx.x * 128 + (w & 1) * 64;
    const int lm = lane & 15;
    const int lk = (lane >> 4) * 8;

    f32x4 acc[2][4] = {};
    #pragma unroll
    for (int ks = 0; ks < 4; ++ks) {
        const int k0 = ks * 32 + lk;
        bf16x8 wf[4], af[2];
        #pragma unroll
        for (int j = 0; j < 4; ++j)
            wf[j] = *(const bf16x8*)(WT + (size_t)(n0 + j * 16 + lm) * IC + k0);
        #pragma unroll
        for (int i = 0; i < 2; ++i)
            af[i] = *(const bf16x8*)(agg + (size_t)(m0 + i * 16 + lm) * IC + k0);
        #pragma unroll
        for (int i = 0; i < 2; ++i)
            #pragma unroll
            for (int j = 0; j < 4; ++j)
                acc[i][j] = __builtin_amdgcn_mfma_f32_16x16x32_bf16(wf[j], af[i], acc[i][j], 0, 0, 0);
    }

    // swapped D layout: col(lane&15) = m-dim, row((lane>>4)*4+reg) = n-dim -> float4 along n
    const int mcol = lane & 15;
    const int nb4 = (lane >> 4) * 4;
    #pragma unroll
    for (int i = 0; i < 2; ++i) {
        int m = m0 + i * 16 + mcol;
        if (m < NN) {
            #pragma unroll
            for (int j = 0; j < 4; ++j) {
                int nn = n0 + j * 16 + nb4;
                float4 bv = *(const float4*)&bias[nn];
                float4 o;
                o.x = acc[i][j][0] + bv.x;
                o.y = acc[i][j][1] + bv.y;
                o.z = acc[i][j][2] + bv.z;
                o.w = acc[i][j][3] + bv.w;
                *(float4*)(out + (size_t)m * OC + nn) = o;
            }
        }
    }
}

// ---------------- launch ----------------
extern "C" void kernel_launch(void* const* d_in, const int* in_sizes, int n_in,
                              void* d_out, int out_size, void* d_ws, size_t ws_size,
                              hipStream_t stream) {
    const float* x  = (const float*)d_in[0];
    const float* W  = (const float*)d_in[1];
    const float* b  = (const float*)d_in[2];
    const int*   ei = (const int*)d_in[3];
    const float* ew = (const float*)d_in[4];
    const int* row = ei;            // source
    const int* col = ei + NE;       // target
    float* out = (float*)d_out;

    char* w0 = (char*)d_ws;
    float* deg   = (float*)w0;                   w0 += NPAD * 4;   // -> dinv in place
    int*   count = (int*)w0;                     w0 += NPAD * 4;   // also fill cursor
    int*   bsum  = (int*)w0;                     w0 += 256 * 4;
    int*   start = (int*)w0;                     w0 += NPAD * 4;
    int2*  epack = (int2*)w0;                    w0 += NE * 8;
    unsigned short* WT   = (unsigned short*)w0;  w0 += IC * OC * 2;
    unsigned short* xb   = (unsigned short*)w0;  w0 += (size_t)NN * IC * 2;
    unsigned short* aggb = (unsigned short*)w0;  // NPAD*IC bf16 = 12.8 MB

    k_init      <<<NB, 256, 0, stream>>>(deg, count);
    k_edge_pass1<<<(NE + 255) / 256, 256, 0, stream>>>(col, ew, deg, count);
    k_dinv      <<<NB, 256, 0, stream>>>(deg);
    k_scan1     <<<NB, 256, 0, stream>>>(count, start, bsum);
    k_scan2     <<<1, 256, 0, stream>>>(bsum);
    k_scan3     <<<NB, 256, 0, stream>>>(start, bsum, count);
    k_fill      <<<(NE + 255) / 256, 256, 0, stream>>>(row, col, ew, deg, start, count, epack);
    k_xb        <<<(NN * (IC / 4) + 255) / 256, 256, 0, stream>>>(x, xb);
    k_wt        <<<(IC * OC) / 256, 256, 0, stream>>>(W, WT);
    k_gather    <<<(NN + 15) / 16, 256, 0, stream>>>(xb, start, epack, deg, aggb);
    k_gemm      <<<dim3(2, (NN + 63) / 64), 256, 0, stream>>>(aggb, WT, b, out);
}

// Round 5
// 177.178 us; speedup vs baseline: 2.2189x; 1.2629x over previous
//
#include <hip/hip_runtime.h>
#include <hip/hip_bf16.h>
#include <math.h>

#define NN 50000
#define NE 500000
#define IC 128
#define OC 256
#define NPAD 50176            // 196 * 256
#define NB 196                // scan blocks
#define NEB 1954              // edge blocks = ceil(NE/256)

typedef short bf16x8 __attribute__((ext_vector_type(8)));
typedef float f32x4 __attribute__((ext_vector_type(4)));

static __device__ inline unsigned short f2b(float f) {
    __hip_bfloat16 h = __float2bfloat16(f);   // RNE
    return *reinterpret_cast<unsigned short*>(&h);
}
static __device__ inline float b2f(short u) {
    unsigned v = ((unsigned)(unsigned short)u) << 16;
    return __int_as_float(v);
}

// ---------------- init: deg64 = (count=0, degfix = 1.0 in 8.24) ----------------
__global__ void k_init(unsigned long long* __restrict__ deg64) {
    int i = blockIdx.x * 256 + threadIdx.x;   // i < NPAD
    deg64[i] = (unsigned long long)(1u << 24);   // self-loop weight 1
}

// ---------------- pass1: single u64 atomic (count|degfix), slot reservation;
//                  fused: x->bf16 and W->WT bf16 conversions ----------------
__global__ void k_pass1(const int* __restrict__ col,
                        const float* __restrict__ ew,
                        unsigned long long* __restrict__ deg64,
                        int* __restrict__ eord,
                        const float* __restrict__ x,
                        unsigned short* __restrict__ xb,
                        const float* __restrict__ W,
                        unsigned short* __restrict__ WT) {
    int g = blockIdx.x * 256 + threadIdx.x;
    if (g < NE) {
        int c = col[g];
        float w = 1.0f / (1.0f + expf(-ew[g]));   // sigmoid
        unsigned long long pack = (1ull << 32) | (unsigned long long)(unsigned)(w * 16777216.0f);
        unsigned long long old = atomicAdd(&deg64[c], pack);
        eord[g] = (int)(old >> 32);               // within-bucket ordinal
    }
    // fused x -> bf16 (latency-bound kernel hides this streaming work)
    const int NX = NN * (IC / 4);
    for (int i = g; i < NX; i += NEB * 256) {
        float4 v = ((const float4*)x)[i];
        ushort4 o;
        o.x = f2b(v.x); o.y = f2b(v.y); o.z = f2b(v.z); o.w = f2b(v.w);
        ((ushort4*)xb)[i] = o;
    }
    // fused W -> W^T bf16
    if (g < IC * OC) {
        int k = g >> 8;
        int n = g & 255;
        WT[n * IC + k] = f2b(W[g]);
    }
}

// ---------------- dinv + block-scan (fused, same grid) ----------------
__global__ void k_dinv_scan(const unsigned long long* __restrict__ deg64,
                            float* __restrict__ dinv,
                            int* __restrict__ sp,
                            int* __restrict__ bsum) {
    __shared__ int s[256];
    int t = threadIdx.x;
    int i = blockIdx.x * 256 + t;
    unsigned long long v = deg64[i];
    int cnt = (int)(v >> 32);
    float deg = (float)(unsigned)v * (1.0f / 16777216.0f);
    dinv[i] = rsqrtf(deg);                    // deg >= 1 always
    s[t] = cnt;
    __syncthreads();
    #pragma unroll
    for (int off = 1; off < 256; off <<= 1) {
        int add = (t >= off) ? s[t - off] : 0;
        __syncthreads();
        s[t] += add;
        __syncthreads();
    }
    sp[i] = s[t] - cnt;                       // exclusive within block
    if (t == 255) bsum[blockIdx.x] = s[255];
}

__global__ void k_scan2(int* __restrict__ bsum) {
    __shared__ int s[256];
    int t = threadIdx.x;
    int v = (t < NB) ? bsum[t] : 0;
    s[t] = v;
    __syncthreads();
    #pragma unroll
    for (int off = 1; off < 256; off <<= 1) {
        int add = (t >= off) ? s[t - off] : 0;
        __syncthreads();
        s[t] += add;
        __syncthreads();
    }
    if (t < NB) bsum[t] = s[t] - v;           // exclusive block offsets
}

// ---------------- fill: NO atomic — slot = sp[t] + bsum[t>>8] + eord[e] ----------------
__global__ void k_fill(const int* __restrict__ row,
                       const int* __restrict__ col,
                       const float* __restrict__ ew,
                       const float* __restrict__ dinv,
                       const int* __restrict__ sp,
                       const int* __restrict__ bsum,
                       const int* __restrict__ eord,
                       int2* __restrict__ epack) {
    int e = blockIdx.x * 256 + threadIdx.x;
    if (e < NE) {
        int r = row[e], t = col[e];
        float w = 1.0f / (1.0f + expf(-ew[e]));
        float nrm = dinv[r] * w * dinv[t];
        int pos = sp[t] + bsum[t >> 8] + eord[e];
        int2 p;
        p.x = r;
        p.y = __float_as_int(nrm);
        epack[pos] = p;                       // one 8B store per edge
    }
}

// ---------------- gather (bf16): aggb[n] = bf16( xb[n]*dinv^2 + sum_e xb[r]*nrm ) ----------------
// 16 nodes per block, 16 lanes per node, bf16x8 (16B) per lane
__global__ __launch_bounds__(256) void k_gather(const unsigned short* __restrict__ xb,
                                                const int* __restrict__ sp,
                                                const int* __restrict__ bsum,
                                                const int2* __restrict__ epack,
                                                const float* __restrict__ dinv,
                                                unsigned short* __restrict__ aggb) {
    int n = blockIdx.x * 16 + (threadIdx.x >> 4);
    if (n >= NN) return;
    int lane = threadIdx.x & 15;
    const bf16x8* xv = (const bf16x8*)xb;     // row = 16 units of 8 bf16

    float di = dinv[n];
    float s2 = di * di;
    bf16x8 xs = xv[(size_t)n * 16 + lane];
    float acc[8];
    #pragma unroll
    for (int c = 0; c < 8; ++c) acc[c] = b2f(xs[c]) * s2;

    int s = sp[n] + bsum[n >> 8];
    int t = sp[n + 1] + bsum[(n + 1) >> 8];
    int e = s;
    for (; e + 2 <= t; e += 2) {
        int2 p0 = epack[e];
        int2 p1 = epack[e + 1];
        bf16x8 v0 = xv[(size_t)p0.x * 16 + lane];
        bf16x8 v1 = xv[(size_t)p1.x * 16 + lane];
        float w0 = __int_as_float(p0.y);
        float w1 = __int_as_float(p1.y);
        #pragma unroll
        for (int c = 0; c < 8; ++c) acc[c] += b2f(v0[c]) * w0;
        #pragma unroll
        for (int c = 0; c < 8; ++c) acc[c] += b2f(v1[c]) * w1;
    }
    if (e < t) {
        int2 p = epack[e];
        bf16x8 v = xv[(size_t)p.x * 16 + lane];
        float w = __int_as_float(p.y);
        #pragma unroll
        for (int c = 0; c < 8; ++c) acc[c] += b2f(v[c]) * w;
    }

    bf16x8 o;
    #pragma unroll
    for (int c = 0; c < 8; ++c) o[c] = (short)f2b(acc[c]);
    ((bf16x8*)aggb)[(size_t)n * 16 + lane] = o;
}

// ---------------- GEMM: out = aggb @ WT^T + b  (MFMA, no LDS, swapped operands) ----------------
// block 256 = 4 waves; block tile 64m x 128n; wave tile 32m x 64n; grid (2, 782)
__global__ __launch_bounds__(256) void k_gemm(const unsigned short* __restrict__ agg,
                                              const unsigned short* __restrict__ WT,
                                              const float* __restrict__ bias,
                                              float* __restrict__ out) {
    const int w = threadIdx.x >> 6;
    const int lane = threadIdx.x & 63;
    const int m0 = blockIdx.y * 64 + (w >> 1) * 32;
    const int n0 = blockIdx.x * 128 + (w & 1) * 64;
    const int lm = lane & 15;
    const int lk = (lane >> 4) * 8;

    f32x4 acc[2][4] = {};
    #pragma unroll
    for (int ks = 0; ks < 4; ++ks) {
        const int k0 = ks * 32 + lk;
        bf16x8 wf[4], af[2];
        #pragma unroll
        for (int j = 0; j < 4; ++j)
            wf[j] = *(const bf16x8*)(WT + (size_t)(n0 + j * 16 + lm) * IC + k0);
        #pragma unroll
        for (int i = 0; i < 2; ++i)
            af[i] = *(const bf16x8*)(agg + (size_t)(m0 + i * 16 + lm) * IC + k0);
        #pragma unroll
        for (int i = 0; i < 2; ++i)
            #pragma unroll
            for (int j = 0; j < 4; ++j)
                acc[i][j] = __builtin_amdgcn_mfma_f32_16x16x32_bf16(wf[j], af[i], acc[i][j], 0, 0, 0);
    }

    // swapped D layout: col(lane&15) = m-dim, row((lane>>4)*4+reg) = n-dim -> float4 along n
    const int mcol = lane & 15;
    const int nb4 = (lane >> 4) * 4;
    #pragma unroll
    for (int i = 0; i < 2; ++i) {
        int m = m0 + i * 16 + mcol;
        if (m < NN) {
            #pragma unroll
            for (int j = 0; j < 4; ++j) {
                int nn = n0 + j * 16 + nb4;
                float4 bv = *(const float4*)&bias[nn];
                float4 o;
                o.x = acc[i][j][0] + bv.x;
                o.y = acc[i][j][1] + bv.y;
                o.z = acc[i][j][2] + bv.z;
                o.w = acc[i][j][3] + bv.w;
                *(float4*)(out + (size_t)m * OC + nn) = o;
            }
        }
    }
}

// ---------------- launch ----------------
extern "C" void kernel_launch(void* const* d_in, const int* in_sizes, int n_in,
                              void* d_out, int out_size, void* d_ws, size_t ws_size,
                              hipStream_t stream) {
    const float* x  = (const float*)d_in[0];
    const float* W  = (const float*)d_in[1];
    const float* b  = (const float*)d_in[2];
    const int*   ei = (const int*)d_in[3];
    const float* ew = (const float*)d_in[4];
    const int* row = ei;            // source
    const int* col = ei + NE;       // target
    float* out = (float*)d_out;

    char* w0 = (char*)d_ws;
    unsigned long long* deg64 = (unsigned long long*)w0;  w0 += NPAD * 8;
    float* dinv  = (float*)w0;                   w0 += NPAD * 4;
    int*   sp    = (int*)w0;                     w0 += NPAD * 4;
    int*   bsum  = (int*)w0;                     w0 += 256 * 4;
    int*   eord  = (int*)w0;                     w0 += NE * 4;
    int2*  epack = (int2*)w0;                    w0 += NE * 8;
    unsigned short* WT   = (unsigned short*)w0;  w0 += IC * OC * 2;
    unsigned short* xb   = (unsigned short*)w0;  w0 += (size_t)NN * IC * 2;
    unsigned short* aggb = (unsigned short*)w0;  // NPAD*IC bf16 = 12.8 MB

    k_init      <<<NB, 256, 0, stream>>>(deg64);
    k_pass1     <<<NEB, 256, 0, stream>>>(col, ew, deg64, eord, x, xb, W, WT);
    k_dinv_scan <<<NB, 256, 0, stream>>>(deg64, dinv, sp, bsum);
    k_scan2     <<<1, 256, 0, stream>>>(bsum);
    k_fill      <<<NEB, 256, 0, stream>>>(row, col, ew, dinv, sp, bsum, eord, epack);
    k_gather    <<<(NN + 15) / 16, 256, 0, stream>>>(xb, sp, bsum, epack, dinv, aggb);
    k_gemm      <<<dim3(2, (NN + 63) / 64), 256, 0, stream>>>(aggb, WT, b, out);
}